// Round 3
// baseline (394.996 us; speedup 1.0000x reference)
//
#include <hip/hip_runtime.h>
#include <stdint.h>

#define BB 64
#define SS 1024
#define CC 512
#define EPS 1e-5f

typedef __attribute__((ext_vector_type(8))) __bf16 bf16x8;
typedef __attribute__((ext_vector_type(8))) unsigned short ushort8v;
typedef __attribute__((ext_vector_type(4))) float f32x4;

__device__ __forceinline__ unsigned short f2bf(float f) {
    unsigned int u = __builtin_bit_cast(unsigned int, f);
    u += 0x7fffu + ((u >> 16) & 1u);   // round-to-nearest-even
    return (unsigned short)(u >> 16);
}

// ---------------- K_prep: fused front end ----------------
// roles by blockIdx.x:
//   [0, 8192):      g = x*lnw -> bf16, transposed Ht[b][c][s]; + per-tile stats partials
//   [8192, 8320):   lnw -> bf16 transposed, stored as Ht[64]
//   [8320, 8448):   lnb -> bf16 transposed, stored as Ht[65]
//   [8448, 9472):   lin_w f32 -> bf16 (same [t][s] layout)
__global__ __launch_bounds__(256) void k_prep(const float* __restrict__ x,
                                              const float* __restrict__ lnw,
                                              const float* __restrict__ lnb,
                                              const float* __restrict__ linw,
                                              unsigned short* __restrict__ Wb,
                                              unsigned short* __restrict__ Ht,
                                              float* __restrict__ psum,
                                              float* __restrict__ psq) {
    const int id = blockIdx.x;
    const int t = threadIdx.x;
    if (id >= 8448) {                       // W convert
        int i = (id - 8448) * 256 + t;
        float4 v = ((const float4*)linw)[i];
        ushort4 o;
        o.x = f2bf(v.x); o.y = f2bf(v.y); o.z = f2bf(v.z); o.w = f2bf(v.w);
        ((ushort4*)Wb)[i] = o;
        return;
    }
    __shared__ uint32_t lds[64 * 33];
    __shared__ float ls[4], lq[4];
    int b, rem;
    const float* src;
    const float* wp;
    if (id < 8192)      { b = id >> 7; rem = id & 127; src = x + (size_t)b * SS * CC; wp = lnw; }
    else if (id < 8320) { b = 64; rem = id - 8192; src = lnw; wp = nullptr; }
    else                { b = 65; rem = id - 8320; src = lnb; wp = nullptr; }
    const int s0 = (rem >> 3) << 6;
    const int c0 = (rem & 7) << 6;
    const int cq = t & 15, spA = t >> 4;
    float sA = 0.f, qA = 0.f;
#pragma unroll
    for (int h = 0; h < 2; ++h) {
        int sp = spA + h * 16;               // s-pair index 0..31
        int sl = s0 + 2 * sp;
        int cc = c0 + 4 * cq;
        size_t xb = (size_t)sl * CC + cc;
        float4 a0 = *(const float4*)(src + xb);
        float4 a1 = *(const float4*)(src + xb + CC);
        float4 g0 = a0, g1 = a1;
        if (wp) {
            float4 w0 = *(const float4*)(wp + xb);
            float4 w1 = *(const float4*)(wp + xb + CC);
            g0.x = a0.x * w0.x; g0.y = a0.y * w0.y; g0.z = a0.z * w0.z; g0.w = a0.w * w0.w;
            g1.x = a1.x * w1.x; g1.y = a1.y * w1.y; g1.z = a1.z * w1.z; g1.w = a1.w * w1.w;
            sA += a0.x + a0.y + a0.z + a0.w + a1.x + a1.y + a1.z + a1.w;
            qA += a0.x*a0.x + a0.y*a0.y + a0.z*a0.z + a0.w*a0.w
                + a1.x*a1.x + a1.y*a1.y + a1.z*a1.z + a1.w*a1.w;
        }
        uint32_t u0 = (uint32_t)f2bf(g0.x) | ((uint32_t)f2bf(g1.x) << 16);
        uint32_t u1 = (uint32_t)f2bf(g0.y) | ((uint32_t)f2bf(g1.y) << 16);
        uint32_t u2 = (uint32_t)f2bf(g0.z) | ((uint32_t)f2bf(g1.z) << 16);
        uint32_t u3 = (uint32_t)f2bf(g0.w) | ((uint32_t)f2bf(g1.w) << 16);
        lds[(4 * cq + 0) * 33 + sp] = u0;
        lds[(4 * cq + 1) * 33 + sp] = u1;
        lds[(4 * cq + 2) * 33 + sp] = u2;
        lds[(4 * cq + 3) * 33 + sp] = u3;
    }
    if (wp) {                                // stats partials (register-only)
        for (int off = 32; off; off >>= 1) {
            sA += __shfl_down(sA, off, 64);
            qA += __shfl_down(qA, off, 64);
        }
        if ((t & 63) == 0) { ls[t >> 6] = sA; lq[t >> 6] = qA; }
    }
    __syncthreads();
    int spq = t & 7, clA = t >> 3;
#pragma unroll
    for (int h = 0; h < 2; ++h) {
        int cl = clA + h * 32;
        uint4 v;
        v.x = lds[cl * 33 + spq * 4 + 0];
        v.y = lds[cl * 33 + spq * 4 + 1];
        v.z = lds[cl * 33 + spq * 4 + 2];
        v.w = lds[cl * 33 + spq * 4 + 3];
        size_t o = (((size_t)b * CC + c0 + cl) * SS + (size_t)s0 + spq * 8) >> 3;
        ((uint4*)Ht)[o] = v;
    }
    if (wp && t == 0) {
        psum[id] = ls[0] + ls[1] + ls[2] + ls[3];
        psq[id]  = lq[0] + lq[1] + lq[2] + lq[3];
    }
}

// ---------------- K_stats2: finalize mu, rsigma per batch ----------------
__global__ __launch_bounds__(128) void k_stats2(const float* __restrict__ psum,
                                                const float* __restrict__ psq,
                                                float* __restrict__ mu,
                                                float* __restrict__ rsg) {
    int b = blockIdx.x, t = threadIdx.x;
    float s = psum[b * 128 + t];
    float q = psq[b * 128 + t];
    for (int off = 32; off; off >>= 1) {
        s += __shfl_down(s, off, 64);
        q += __shfl_down(q, off, 64);
    }
    __shared__ float ls[2], lq[2];
    if ((t & 63) == 0) { ls[t >> 6] = s; lq[t >> 6] = q; }
    __syncthreads();
    if (t == 0) {
        float ss = ls[0] + ls[1], qq = lq[0] + lq[1];
        const float inv = 1.f / (float)(SS * CC);
        float m = ss * inv;
        float v = qq * inv - m * m;
        mu[b] = m;
        rsg[b] = rsqrtf(v + EPS);
    }
}

// ---------------- K_gemm: 2-phase pipelined 128x128 tile ----------------
// FINAL=false: batches {64,65} -> Wl = W@lnw_t, Blp = W@lnb_t + lin_b (f32, [z][t][c])
// FINAL=true:  batches 0..63, epilogue out = x + relu(rs*acc - rs*mu*Wl + Blp)
template<bool FINAL>
__global__ __launch_bounds__(256) void k_gemm(const unsigned short* __restrict__ A,
                                              const unsigned short* __restrict__ Htall,
                                              const float* __restrict__ x,
                                              const float* __restrict__ linb,
                                              const float* __restrict__ wl,
                                              const float* __restrict__ blp,
                                              const float* __restrict__ muA,
                                              const float* __restrict__ rsA,
                                              float* __restrict__ out) {
    int b, tm, tn;
    if constexpr (FINAL) {
        // bijective XCD swizzle (2048 % 8 == 0): each XCD gets 8 contiguous batches
        int wg = ((blockIdx.x & 7) << 8) | (blockIdx.x >> 3);
        b = wg >> 5;
        int r2 = wg & 31;
        tm = r2 >> 2; tn = r2 & 3;
    } else {
        tn = blockIdx.x; tm = blockIdx.y; b = 64 + blockIdx.z;
    }
    __shared__ __align__(16) unsigned short SM[16384];   // As[2][4096] | Bs[2][4096] = 32 KB
    const int tid = threadIdx.x;
    const int lane = tid & 63;
    const int w = tid >> 6;
    const int wm = w >> 1, wn = w & 1;
    const int quad = lane >> 4, l15 = lane & 15;

    f32x4 acc[4][4];
#pragma unroll
    for (int mi = 0; mi < 4; ++mi)
#pragma unroll
        for (int ni = 0; ni < 4; ++ni)
            acc[mi][ni] = (f32x4){0.f, 0.f, 0.f, 0.f};

    const unsigned short* Ab = A + (size_t)(tm * 128) * 1024;
    const unsigned short* Bb = Htall + ((size_t)b * 512 + tn * 128) * 1024;
    const int srow = tid >> 2;
    const int scol = (tid & 3) * 8;

    auto stage = [&](int buf, int k0) {
#pragma unroll
        for (int q = 0; q < 2; ++q) {
            __builtin_amdgcn_global_load_lds(
                (const __attribute__((address_space(1))) void*)(Ab + (size_t)(q * 64 + srow) * 1024 + k0 + scol),
                (__attribute__((address_space(3))) void*)(SM + buf * 4096 + q * 2048 + w * 512),
                16, 0, 0);
            __builtin_amdgcn_global_load_lds(
                (const __attribute__((address_space(1))) void*)(Bb + (size_t)(q * 64 + srow) * 1024 + k0 + scol),
                (__attribute__((address_space(3))) void*)(SM + 8192 + buf * 4096 + q * 2048 + w * 512),
                16, 0, 0);
        }
    };
    auto compute = [&](int buf) {
        const unsigned short* as = SM + buf * 4096;
        const unsigned short* bs = SM + 8192 + buf * 4096;
        bf16x8 av[4], bv[4];
#pragma unroll
        for (int i = 0; i < 4; ++i) {
            ushort8v a  = *(const ushort8v*)&as[(wm * 64 + i * 16 + l15) * 32 + quad * 8];
            ushort8v b2 = *(const ushort8v*)&bs[(wn * 64 + i * 16 + l15) * 32 + quad * 8];
            av[i] = __builtin_bit_cast(bf16x8, a);
            bv[i] = __builtin_bit_cast(bf16x8, b2);
        }
#pragma unroll
        for (int mi = 0; mi < 4; ++mi)
#pragma unroll
            for (int ni = 0; ni < 4; ++ni)
                acc[mi][ni] = __builtin_amdgcn_mfma_f32_16x16x32_bf16(
                    av[mi], bv[ni], acc[mi][ni], 0, 0, 0);
    };

    // 2-phase pipeline: stage(next) issued BEFORE compute(current); one barrier/step.
    // Safety: each stage targets the buffer whose reads completed before the prior
    // barrier; barrier's implicit vmcnt(0) drain makes staged data visible.
    stage(0, 0);
    __syncthreads();
    for (int j = 0; j < 15; ++j) {
        int k0 = j * 64;
        stage(1, k0 + 32);
        compute(0);
        __syncthreads();
        stage(0, k0 + 64);
        compute(1);
        __syncthreads();
    }
    stage(1, 992);
    compute(0);
    __syncthreads();
    compute(1);

    if constexpr (FINAL) {
        __syncthreads();                     // all frag reads done -> LDS reusable
        const float rsv  = rsA[b];
        const float rsmu = rsv * muA[b];
        float* eps = (float*)SM + (w << 11); // per-wave 8 KB retile region (32 rows x 64 cols)
#pragma unroll
        for (int ch = 0; ch < 2; ++ch) {
#pragma unroll
            for (int m2 = 0; m2 < 2; ++m2) {
                int mi = ch * 2 + m2;
                // row within 32-row chunk = m2*16 + quad*4 + r
#pragma unroll
                for (int ni = 0; ni < 4; ++ni)
#pragma unroll
                    for (int r = 0; r < 4; ++r)
                        eps[(m2 * 16 + quad * 4 + r) * 64 + ni * 16 + l15] = acc[mi][ni][r];
            }
#pragma unroll
            for (int jj = 0; jj < 8; ++jj) {
                int row = jj * 4 + quad;     // 0..31 within chunk
                int tt = tm * 128 + wm * 64 + ch * 32 + row;
                int cc = tn * 128 + wn * 64 + l15 * 4;
                size_t o2 = (size_t)tt * 512 + cc;
                size_t o  = ((size_t)b * 1024 + tt) * 512 + cc;
                f32x4 v   = *(f32x4*)&eps[row * 64 + l15 * 4];
                f32x4 wv  = *(const f32x4*)&wl[o2];
                f32x4 bv2 = *(const f32x4*)&blp[o2];
                f32x4 xv  = *(const f32x4*)&x[o];
                f32x4 ov;
#pragma unroll
                for (int e = 0; e < 4; ++e) {
                    float vv = rsv * v[e] - rsmu * wv[e] + bv2[e];
                    vv = vv > 0.f ? vv : 0.f;
                    ov[e] = xv[e] + vv;
                }
                *(f32x4*)&out[o] = ov;
            }
            // ch=1 overwrites eps: same-wave DS ordering + compiler lgkm waits
        }
    } else {
        int z = b - 64;
#pragma unroll
        for (int mi = 0; mi < 4; ++mi) {
#pragma unroll
            for (int r = 0; r < 4; ++r) {
                int tt = tm * 128 + wm * 64 + mi * 16 + quad * 4 + r;
                float add = z ? linb[tt] : 0.f;
#pragma unroll
                for (int ni = 0; ni < 4; ++ni) {
                    int cc = tn * 128 + wn * 64 + ni * 16 + l15;
                    out[((size_t)z * 1024 + tt) * 512 + cc] = acc[mi][ni][r] + add;
                }
            }
        }
    }
}

extern "C" void kernel_launch(void* const* d_in, const int* in_sizes, int n_in,
                              void* d_out, int out_size, void* d_ws, size_t ws_size,
                              hipStream_t stream) {
    (void)in_sizes; (void)n_in; (void)out_size; (void)ws_size;
    const float* x    = (const float*)d_in[0];
    const float* lnw  = (const float*)d_in[1];
    const float* lnb  = (const float*)d_in[2];
    const float* linw = (const float*)d_in[3];
    const float* linb = (const float*)d_in[4];
    float* out = (float*)d_out;

    char* ws = (char*)d_ws;
    unsigned short* Wb = (unsigned short*)ws;                 // 2 MB
    unsigned short* Ht = (unsigned short*)(ws + (2u << 20));  // 66 MB (66 batches: x*lnw, lnw, lnb)
    float* wlblp = (float*)(ws + (68u << 20));                // 4 MB: Wl [1024][512], Blp [1024][512]
    float* psum  = (float*)(ws + (72u << 20));                // 32 KB
    float* psq   = psum + 8192;                               // 32 KB
    float* mu    = psq + 8192;
    float* rsg   = mu + 64;

    k_prep<<<9472, 256, 0, stream>>>(x, lnw, lnb, linw, Wb, Ht, psum, psq);
    k_stats2<<<64, 128, 0, stream>>>(psum, psq, mu, rsg);
    k_gemm<false><<<dim3(4, 8, 2), 256, 0, stream>>>(Wb, Ht, nullptr, linb,
                                                     nullptr, nullptr, nullptr, nullptr, wlblp);
    k_gemm<true><<<2048, 256, 0, stream>>>(Wb, Ht, x, nullptr,
                                           wlblp, wlblp + 512 * 1024, mu, rsg, out);
}

// Round 5
// 384.454 us; speedup vs baseline: 1.0274x; 1.0274x over previous
//
#include <hip/hip_runtime.h>
#include <stdint.h>

#define BB 64
#define SS 1024
#define CC 512
#define EPS 1e-5f

typedef __attribute__((ext_vector_type(8))) __bf16 bf16x8;
typedef __attribute__((ext_vector_type(8))) unsigned short ushort8v;
typedef __attribute__((ext_vector_type(4))) float f32x4;

__device__ __forceinline__ unsigned short f2bf(float f) {
    unsigned int u = __builtin_bit_cast(unsigned int, f);
    u += 0x7fffu + ((u >> 16) & 1u);   // round-to-nearest-even
    return (unsigned short)(u >> 16);
}
__device__ __forceinline__ float bf2f(unsigned short u) {
    return __builtin_bit_cast(float, (uint32_t)u << 16);
}

// ---------------- K_prep: fused front end (unchanged from R3) ----------------
__global__ __launch_bounds__(256) void k_prep(const float* __restrict__ x,
                                              const float* __restrict__ lnw,
                                              const float* __restrict__ lnb,
                                              const float* __restrict__ linw,
                                              unsigned short* __restrict__ Wb,
                                              unsigned short* __restrict__ Ht,
                                              float* __restrict__ psum,
                                              float* __restrict__ psq) {
    const int id = blockIdx.x;
    const int t = threadIdx.x;
    if (id >= 8448) {                       // W convert
        int i = (id - 8448) * 256 + t;
        float4 v = ((const float4*)linw)[i];
        ushort4 o;
        o.x = f2bf(v.x); o.y = f2bf(v.y); o.z = f2bf(v.z); o.w = f2bf(v.w);
        ((ushort4*)Wb)[i] = o;
        return;
    }
    __shared__ uint32_t lds[64 * 33];
    __shared__ float ls[4], lq[4];
    int b, rem;
    const float* src;
    const float* wp;
    if (id < 8192)      { b = id >> 7; rem = id & 127; src = x + (size_t)b * SS * CC; wp = lnw; }
    else if (id < 8320) { b = 64; rem = id - 8192; src = lnw; wp = nullptr; }
    else                { b = 65; rem = id - 8320; src = lnb; wp = nullptr; }
    const int s0 = (rem >> 3) << 6;
    const int c0 = (rem & 7) << 6;
    const int cq = t & 15, spA = t >> 4;
    float sA = 0.f, qA = 0.f;
#pragma unroll
    for (int h = 0; h < 2; ++h) {
        int sp = spA + h * 16;
        int sl = s0 + 2 * sp;
        int cc = c0 + 4 * cq;
        size_t xb = (size_t)sl * CC + cc;
        float4 a0 = *(const float4*)(src + xb);
        float4 a1 = *(const float4*)(src + xb + CC);
        float4 g0 = a0, g1 = a1;
        if (wp) {
            float4 w0 = *(const float4*)(wp + xb);
            float4 w1 = *(const float4*)(wp + xb + CC);
            g0.x = a0.x * w0.x; g0.y = a0.y * w0.y; g0.z = a0.z * w0.z; g0.w = a0.w * w0.w;
            g1.x = a1.x * w1.x; g1.y = a1.y * w1.y; g1.z = a1.z * w1.z; g1.w = a1.w * w1.w;
            sA += a0.x + a0.y + a0.z + a0.w + a1.x + a1.y + a1.z + a1.w;
            qA += a0.x*a0.x + a0.y*a0.y + a0.z*a0.z + a0.w*a0.w
                + a1.x*a1.x + a1.y*a1.y + a1.z*a1.z + a1.w*a1.w;
        }
        uint32_t u0 = (uint32_t)f2bf(g0.x) | ((uint32_t)f2bf(g1.x) << 16);
        uint32_t u1 = (uint32_t)f2bf(g0.y) | ((uint32_t)f2bf(g1.y) << 16);
        uint32_t u2 = (uint32_t)f2bf(g0.z) | ((uint32_t)f2bf(g1.z) << 16);
        uint32_t u3 = (uint32_t)f2bf(g0.w) | ((uint32_t)f2bf(g1.w) << 16);
        lds[(4 * cq + 0) * 33 + sp] = u0;
        lds[(4 * cq + 1) * 33 + sp] = u1;
        lds[(4 * cq + 2) * 33 + sp] = u2;
        lds[(4 * cq + 3) * 33 + sp] = u3;
    }
    if (wp) {
        for (int off = 32; off; off >>= 1) {
            sA += __shfl_down(sA, off, 64);
            qA += __shfl_down(qA, off, 64);
        }
        if ((t & 63) == 0) { ls[t >> 6] = sA; lq[t >> 6] = qA; }
    }
    __syncthreads();
    int spq = t & 7, clA = t >> 3;
#pragma unroll
    for (int h = 0; h < 2; ++h) {
        int cl = clA + h * 32;
        uint4 v;
        v.x = lds[cl * 33 + spq * 4 + 0];
        v.y = lds[cl * 33 + spq * 4 + 1];
        v.z = lds[cl * 33 + spq * 4 + 2];
        v.w = lds[cl * 33 + spq * 4 + 3];
        size_t o = (((size_t)b * CC + c0 + cl) * SS + (size_t)s0 + spq * 8) >> 3;
        ((uint4*)Ht)[o] = v;
    }
    if (wp && t == 0) {
        psum[id] = ls[0] + ls[1] + ls[2] + ls[3];
        psq[id]  = lq[0] + lq[1] + lq[2] + lq[3];
    }
}

// ---------------- K_stats2 (unchanged) ----------------
__global__ __launch_bounds__(128) void k_stats2(const float* __restrict__ psum,
                                                const float* __restrict__ psq,
                                                float* __restrict__ mu,
                                                float* __restrict__ rsg) {
    int b = blockIdx.x, t = threadIdx.x;
    float s = psum[b * 128 + t];
    float q = psq[b * 128 + t];
    for (int off = 32; off; off >>= 1) {
        s += __shfl_down(s, off, 64);
        q += __shfl_down(q, off, 64);
    }
    __shared__ float ls[2], lq[2];
    if ((t & 63) == 0) { ls[t >> 6] = s; lq[t >> 6] = q; }
    __syncthreads();
    if (t == 0) {
        float ss = ls[0] + ls[1], qq = lq[0] + lq[1];
        const float inv = 1.f / (float)(SS * CC);
        float m = ss * inv;
        float v = qq * inv - m * m;
        mu[b] = m;
        rsg[b] = rsqrtf(v + EPS);
    }
}

// ---------------- K_gemm: 3-deep counted-vmcnt pipeline, swizzled LDS ----------------
// FINAL=false: batches {64,65} -> Wl_bf16, Blp_bf16 (= W@lnb_t + lin_b)
// FINAL=true:  batches 0..63, epilogue out = x + relu(rs*acc - rs*mu*Wl + Blp)
template<bool FINAL>
__global__ __launch_bounds__(256) void k_gemm(const unsigned short* __restrict__ A,
                                              const unsigned short* __restrict__ Htall,
                                              const float* __restrict__ x,
                                              const float* __restrict__ linb,
                                              const unsigned short* __restrict__ wlb,
                                              const unsigned short* __restrict__ blb,
                                              const float* __restrict__ muA,
                                              const float* __restrict__ rsA,
                                              float* __restrict__ out) {
    int b, tm, tn;
    if constexpr (FINAL) {
        // XCD-aware: xcd = bid&7 (round-robin dispatch). Within XCD: batch-major,
        // tn, then tm innermost -> B panel (b,tn) reused by 8 consecutive blocks (L2);
        // A (2MB) + wl/blp bf16 (2MB) stay L2-resident.
        int xcd = blockIdx.x & 7;
        int local = blockIdx.x >> 3;          // 0..255
        b = xcd * 8 + (local >> 5);
        tn = (local >> 3) & 3;
        tm = local & 7;
    } else {
        tn = blockIdx.x; tm = blockIdx.y; b = 64 + blockIdx.z;
    }
    // 3 buffers x (A 4096 + B 4096) shorts = 48 KB
    __shared__ __align__(16) unsigned short SM[24576];
    const int tid = threadIdx.x;
    const int lane = tid & 63;
    const int w = tid >> 6;
    const int wm = w >> 1, wn = w & 1;
    const int quad = lane >> 4, l15 = lane & 15;

    f32x4 acc[4][4];
#pragma unroll
    for (int mi = 0; mi < 4; ++mi)
#pragma unroll
        for (int ni = 0; ni < 4; ++ni)
            acc[mi][ni] = (f32x4){0.f, 0.f, 0.f, 0.f};

    const unsigned short* Ab = A + (size_t)(tm * 128) * 1024;
    const unsigned short* Bb = Htall + ((size_t)b * 512 + tn * 128) * 1024;
    const int srow = tid >> 2;                              // 0..63
    // XOR slot swizzle: LDS(row, s) holds global(row, s ^ ((row>>1)&3)).
    // gload_lds dest is linear (rule 21) -> permute the GLOBAL source slot.
    const int scol = ((tid & 3) ^ ((srow >> 1) & 3)) * 8;   // shorts

    auto stage = [&](int buf, int k0) {
#pragma unroll
        for (int q = 0; q < 2; ++q) {
            __builtin_amdgcn_global_load_lds(
                (const __attribute__((address_space(1))) void*)(Ab + (size_t)(q * 64 + srow) * 1024 + k0 + scol),
                (__attribute__((address_space(3))) void*)(SM + buf * 8192 + q * 2048 + w * 512),
                16, 0, 0);
            __builtin_amdgcn_global_load_lds(
                (const __attribute__((address_space(1))) void*)(Bb + (size_t)(q * 64 + srow) * 1024 + k0 + scol),
                (__attribute__((address_space(3))) void*)(SM + buf * 8192 + 4096 + q * 2048 + w * 512),
                16, 0, 0);
        }
    };
    const int fs = (l15 >> 1) & 3;   // read-side swizzle: row = **64+i*16+l15 -> f(row)=(l15>>1)&3
    auto compute = [&](int buf) {
        const unsigned short* as = SM + buf * 8192;
        const unsigned short* bs = SM + buf * 8192 + 4096;
        bf16x8 av[4], bv[4];
#pragma unroll
        for (int i = 0; i < 4; ++i) {
            ushort8v a  = *(const ushort8v*)&as[(wm * 64 + i * 16 + l15) * 32 + (quad ^ fs) * 8];
            ushort8v b2 = *(const ushort8v*)&bs[(wn * 64 + i * 16 + l15) * 32 + (quad ^ fs) * 8];
            av[i] = __builtin_bit_cast(bf16x8, a);
            bv[i] = __builtin_bit_cast(bf16x8, b2);
        }
#pragma unroll
        for (int mi = 0; mi < 4; ++mi)
#pragma unroll
            for (int ni = 0; ni < 4; ++ni)
                acc[mi][ni] = __builtin_amdgcn_mfma_f32_16x16x32_bf16(
                    av[mi], bv[ni], acc[mi][ni], 0, 0, 0);
    };

    // 3-deep pipeline, counted vmcnt (never 0 in steady state).
    // Invariant at iter j entry: outstanding = stages {j, j+1} (8 loads).
    // vmcnt(4) -> stage j complete; barrier -> all waves' stage j complete and
    // all waves' compute(j-1) reads retired (lgkm drained by MFMA consumption)
    // -> safe to issue stage(j+2) into buf (j-1)%3.
    stage(0, 0);
    stage(1, 32);
    for (int j = 0; j < 31; ++j) {
        asm volatile("s_waitcnt vmcnt(4)" ::: "memory");
        __builtin_amdgcn_sched_barrier(0);
        __builtin_amdgcn_s_barrier();
        __builtin_amdgcn_sched_barrier(0);
        int k2 = (j + 2) * 32;
        if (k2 < 1024) stage((j + 2) % 3, k2);
        compute(j % 3);
    }
    asm volatile("s_waitcnt vmcnt(0)" ::: "memory");
    __builtin_amdgcn_sched_barrier(0);
    __builtin_amdgcn_s_barrier();
    __builtin_amdgcn_sched_barrier(0);
    compute(31 % 3);   // buf 1

    if constexpr (FINAL) {
        __syncthreads();                     // all frag reads done -> LDS reusable
        const float rsv  = rsA[b];
        const float rsmu = rsv * muA[b];
        float* eps = (float*)SM + (w << 11); // per-wave 8 KB retile (32 rows x 64 cols)
#pragma unroll
        for (int ch = 0; ch < 2; ++ch) {
#pragma unroll
            for (int m2 = 0; m2 < 2; ++m2) {
                int mi = ch * 2 + m2;        // row in chunk = m2*16 + quad*4 + r
#pragma unroll
                for (int ni = 0; ni < 4; ++ni)
#pragma unroll
                    for (int r = 0; r < 4; ++r)
                        eps[(m2 * 16 + quad * 4 + r) * 64 + ni * 16 + l15] = acc[mi][ni][r];
            }
#pragma unroll
            for (int jj = 0; jj < 8; ++jj) {
                int row = jj * 4 + quad;     // 0..31 within chunk
                int tt = tm * 128 + wm * 64 + ch * 32 + row;
                int cc = tn * 128 + wn * 64 + l15 * 4;
                size_t o2 = (size_t)tt * 512 + cc;
                size_t o  = ((size_t)b * 1024 + tt) * 512 + cc;
                f32x4 v    = *(f32x4*)&eps[row * 64 + l15 * 4];
                ushort4 wv4 = *(const ushort4*)&wlb[o2];
                ushort4 bv4 = *(const ushort4*)&blb[o2];
                f32x4 xv   = *(const f32x4*)&x[o];
                float we[4] = {bf2f(wv4.x), bf2f(wv4.y), bf2f(wv4.z), bf2f(wv4.w)};
                float be[4] = {bf2f(bv4.x), bf2f(bv4.y), bf2f(bv4.z), bf2f(bv4.w)};
                f32x4 ov;
#pragma unroll
                for (int e = 0; e < 4; ++e) {
                    float vv = rsv * v[e] - rsmu * we[e] + be[e];
                    vv = vv > 0.f ? vv : 0.f;
                    ov[e] = xv[e] + vv;
                }
                *(f32x4*)&out[o] = ov;
            }
            // ch=1 overwrites eps: same-wave DS ordering + compiler lgkm waits
        }
    } else {
        int z = b - 64;
        unsigned short* o16 = (unsigned short*)out;
#pragma unroll
        for (int mi = 0; mi < 4; ++mi) {
#pragma unroll
            for (int r = 0; r < 4; ++r) {
                int tt = tm * 128 + wm * 64 + mi * 16 + quad * 4 + r;
                float add = z ? linb[tt] : 0.f;
#pragma unroll
                for (int ni = 0; ni < 4; ++ni) {
                    int cc = tn * 128 + wn * 64 + ni * 16 + l15;
                    o16[((size_t)z * 1024 + tt) * 512 + cc] = f2bf(acc[mi][ni][r] + add);
                }
            }
        }
    }
}

extern "C" void kernel_launch(void* const* d_in, const int* in_sizes, int n_in,
                              void* d_out, int out_size, void* d_ws, size_t ws_size,
                              hipStream_t stream) {
    (void)in_sizes; (void)n_in; (void)out_size; (void)ws_size;
    const float* x    = (const float*)d_in[0];
    const float* lnw  = (const float*)d_in[1];
    const float* lnb  = (const float*)d_in[2];
    const float* linw = (const float*)d_in[3];
    const float* linb = (const float*)d_in[4];
    float* out = (float*)d_out;

    char* ws = (char*)d_ws;
    unsigned short* Wb  = (unsigned short*)ws;                 // 2 MB
    unsigned short* Ht  = (unsigned short*)(ws + (2u << 20));  // 66 MB (66 batches)
    unsigned short* wlb = (unsigned short*)(ws + (68u << 20)); // 1 MB  Wl bf16 [1024][512]
    unsigned short* blb = wlb + 512 * 1024;                    // 1 MB  Blp bf16
    float* psum = (float*)(ws + (72u << 20));                  // 32 KB
    float* psq  = psum + 8192;                                 // 32 KB
    float* mu   = psq + 8192;
    float* rsg  = mu + 64;

    k_prep<<<9472, 256, 0, stream>>>(x, lnw, lnb, linw, Wb, Ht, psum, psq);
    k_stats2<<<64, 128, 0, stream>>>(psum, psq, mu, rsg);
    k_gemm<false><<<dim3(4, 8, 2), 256, 0, stream>>>(Wb, Ht, nullptr, linb,
                                                     nullptr, nullptr, nullptr, nullptr,
                                                     (float*)wlb);
    k_gemm<true><<<2048, 256, 0, stream>>>(Wb, Ht, x, nullptr,
                                           wlb, blb, mu, rsg, out);
}

// Round 7
// 364.673 us; speedup vs baseline: 1.0832x; 1.0542x over previous
//
#include <hip/hip_runtime.h>
#include <stdint.h>

#define BB 64
#define SS 1024
#define CC 512
#define EPS 1e-5f

typedef __attribute__((ext_vector_type(8))) __bf16 bf16x8;
typedef __attribute__((ext_vector_type(8))) unsigned short ushort8v;
typedef __attribute__((ext_vector_type(4))) float f32x4;

__device__ __forceinline__ unsigned short f2bf(float f) {
    unsigned int u = __builtin_bit_cast(unsigned int, f);
    u += 0x7fffu + ((u >> 16) & 1u);   // round-to-nearest-even
    return (unsigned short)(u >> 16);
}
__device__ __forceinline__ float bf2f(unsigned short u) {
    return __builtin_bit_cast(float, (uint32_t)u << 16);
}

// ---------------- K_prep: fused front end (unchanged from R5) ----------------
__global__ __launch_bounds__(256) void k_prep(const float* __restrict__ x,
                                              const float* __restrict__ lnw,
                                              const float* __restrict__ lnb,
                                              const float* __restrict__ linw,
                                              unsigned short* __restrict__ Wb,
                                              unsigned short* __restrict__ Ht,
                                              float* __restrict__ psum,
                                              float* __restrict__ psq) {
    const int id = blockIdx.x;
    const int t = threadIdx.x;
    if (id >= 8448) {                       // W convert
        int i = (id - 8448) * 256 + t;
        float4 v = ((const float4*)linw)[i];
        ushort4 o;
        o.x = f2bf(v.x); o.y = f2bf(v.y); o.z = f2bf(v.z); o.w = f2bf(v.w);
        ((ushort4*)Wb)[i] = o;
        return;
    }
    __shared__ uint32_t lds[64 * 33];
    __shared__ float ls[4], lq[4];
    int b, rem;
    const float* src;
    const float* wp;
    if (id < 8192)      { b = id >> 7; rem = id & 127; src = x + (size_t)b * SS * CC; wp = lnw; }
    else if (id < 8320) { b = 64; rem = id - 8192; src = lnw; wp = nullptr; }
    else                { b = 65; rem = id - 8320; src = lnb; wp = nullptr; }
    const int s0 = (rem >> 3) << 6;
    const int c0 = (rem & 7) << 6;
    const int cq = t & 15, spA = t >> 4;
    float sA = 0.f, qA = 0.f;
#pragma unroll
    for (int h = 0; h < 2; ++h) {
        int sp = spA + h * 16;
        int sl = s0 + 2 * sp;
        int cc = c0 + 4 * cq;
        size_t xb = (size_t)sl * CC + cc;
        float4 a0 = *(const float4*)(src + xb);
        float4 a1 = *(const float4*)(src + xb + CC);
        float4 g0 = a0, g1 = a1;
        if (wp) {
            float4 w0 = *(const float4*)(wp + xb);
            float4 w1 = *(const float4*)(wp + xb + CC);
            g0.x = a0.x * w0.x; g0.y = a0.y * w0.y; g0.z = a0.z * w0.z; g0.w = a0.w * w0.w;
            g1.x = a1.x * w1.x; g1.y = a1.y * w1.y; g1.z = a1.z * w1.z; g1.w = a1.w * w1.w;
            sA += a0.x + a0.y + a0.z + a0.w + a1.x + a1.y + a1.z + a1.w;
            qA += a0.x*a0.x + a0.y*a0.y + a0.z*a0.z + a0.w*a0.w
                + a1.x*a1.x + a1.y*a1.y + a1.z*a1.z + a1.w*a1.w;
        }
        uint32_t u0 = (uint32_t)f2bf(g0.x) | ((uint32_t)f2bf(g1.x) << 16);
        uint32_t u1 = (uint32_t)f2bf(g0.y) | ((uint32_t)f2bf(g1.y) << 16);
        uint32_t u2 = (uint32_t)f2bf(g0.z) | ((uint32_t)f2bf(g1.z) << 16);
        uint32_t u3 = (uint32_t)f2bf(g0.w) | ((uint32_t)f2bf(g1.w) << 16);
        lds[(4 * cq + 0) * 33 + sp] = u0;
        lds[(4 * cq + 1) * 33 + sp] = u1;
        lds[(4 * cq + 2) * 33 + sp] = u2;
        lds[(4 * cq + 3) * 33 + sp] = u3;
    }
    if (wp) {
        for (int off = 32; off; off >>= 1) {
            sA += __shfl_down(sA, off, 64);
            qA += __shfl_down(qA, off, 64);
        }
        if ((t & 63) == 0) { ls[t >> 6] = sA; lq[t >> 6] = qA; }
    }
    __syncthreads();
    int spq = t & 7, clA = t >> 3;
#pragma unroll
    for (int h = 0; h < 2; ++h) {
        int cl = clA + h * 32;
        uint4 v;
        v.x = lds[cl * 33 + spq * 4 + 0];
        v.y = lds[cl * 33 + spq * 4 + 1];
        v.z = lds[cl * 33 + spq * 4 + 2];
        v.w = lds[cl * 33 + spq * 4 + 3];
        size_t o = (((size_t)b * CC + c0 + cl) * SS + (size_t)s0 + spq * 8) >> 3;
        ((uint4*)Ht)[o] = v;
    }
    if (wp && t == 0) {
        psum[id] = ls[0] + ls[1] + ls[2] + ls[3];
        psq[id]  = lq[0] + lq[1] + lq[2] + lq[3];
    }
}

// ---------------- K_stats2 (unchanged) ----------------
__global__ __launch_bounds__(128) void k_stats2(const float* __restrict__ psum,
                                                const float* __restrict__ psq,
                                                float* __restrict__ mu,
                                                float* __restrict__ rsg) {
    int b = blockIdx.x, t = threadIdx.x;
    float s = psum[b * 128 + t];
    float q = psq[b * 128 + t];
    for (int off = 32; off; off >>= 1) {
        s += __shfl_down(s, off, 64);
        q += __shfl_down(q, off, 64);
    }
    __shared__ float ls[2], lq[2];
    if ((t & 63) == 0) { ls[t >> 6] = s; lq[t >> 6] = q; }
    __syncthreads();
    if (t == 0) {
        float ss = ls[0] + ls[1], qq = lq[0] + lq[1];
        const float inv = 1.f / (float)(SS * CC);
        float m = ss * inv;
        float v = qq * inv - m * m;
        mu[b] = m;
        rsg[b] = rsqrtf(v + EPS);
    }
}

// ---------------- K_gemm: batch-PAIRED 128x128 tile, 3-deep counted vmcnt ----------------
// Each block computes tile (tm,tn) for TWO batches sharing the A (weight) staging:
// stage = A + B0 + B1 (6 loads), compute = 32 MFMA on two independent accumulators.
// FINAL=false: pair {64,65} -> Wl_bf16 / Blp_bf16.  FINAL=true: pairs {2p,2p+1}.
template<bool FINAL>
__global__ __launch_bounds__(256, 2) void k_gemm(const unsigned short* __restrict__ A,
                                                 const unsigned short* __restrict__ Htall,
                                                 const float* __restrict__ x,
                                                 const float* __restrict__ linb,
                                                 const unsigned short* __restrict__ wlb,
                                                 const unsigned short* __restrict__ blb,
                                                 const float* __restrict__ muA,
                                                 const float* __restrict__ rsA,
                                                 float* __restrict__ out) {
    int b0, b1, tm, tn;
    if constexpr (FINAL) {
        // 1024 blocks = 8 XCD x (4 pairs x 4 tn x 8 tm). tm innermost -> 8 consecutive
        // blocks share the (pair,tn) B panels in L2; A (2MB) + wl/blp (2MB) L2-resident.
        int xcd = blockIdx.x & 7;
        int local = blockIdx.x >> 3;          // 0..127
        int p = xcd * 4 + (local >> 5);       // batch pair 0..31
        int rem = local & 31;
        tn = rem >> 3; tm = rem & 7;
        b0 = 2 * p; b1 = 2 * p + 1;
    } else {
        tn = blockIdx.x; tm = blockIdx.y; b0 = 64; b1 = 65;
    }
    // 3 buffers x (A 4096 + B0 4096 + B1 4096) shorts = 72 KB
    __shared__ __align__(16) unsigned short SM[36864];
    const int tid = threadIdx.x;
    const int lane = tid & 63;
    const int w = tid >> 6;
    const int wm = w >> 1, wn = w & 1;
    const int quad = lane >> 4, l15 = lane & 15;

    f32x4 acc0[4][4], acc1[4][4];
#pragma unroll
    for (int mi = 0; mi < 4; ++mi)
#pragma unroll
        for (int ni = 0; ni < 4; ++ni) {
            acc0[mi][ni] = (f32x4){0.f, 0.f, 0.f, 0.f};
            acc1[mi][ni] = (f32x4){0.f, 0.f, 0.f, 0.f};
        }

    const unsigned short* Ab  = A + (size_t)(tm * 128) * 1024;
    const unsigned short* Bb0 = Htall + ((size_t)b0 * 512 + tn * 128) * 1024;
    const unsigned short* Bb1 = Htall + ((size_t)b1 * 512 + tn * 128) * 1024;
    const int srow = tid >> 2;                              // 0..63
    // XOR slot swizzle (kept from R5): LDS(row,s) = global(row, s ^ ((row>>1)&3)).
    const int scol = ((tid & 3) ^ ((srow >> 1) & 3)) * 8;   // shorts

    auto stage = [&](int buf, int k0) {
        unsigned short* base = SM + buf * 12288;
#pragma unroll
        for (int q = 0; q < 2; ++q) {
            size_t roff = (size_t)(q * 64 + srow) * 1024 + k0 + scol;
            __builtin_amdgcn_global_load_lds(
                (const __attribute__((address_space(1))) void*)(Ab + roff),
                (__attribute__((address_space(3))) void*)(base + q * 2048 + w * 512), 16, 0, 0);
            __builtin_amdgcn_global_load_lds(
                (const __attribute__((address_space(1))) void*)(Bb0 + roff),
                (__attribute__((address_space(3))) void*)(base + 4096 + q * 2048 + w * 512), 16, 0, 0);
            __builtin_amdgcn_global_load_lds(
                (const __attribute__((address_space(1))) void*)(Bb1 + roff),
                (__attribute__((address_space(3))) void*)(base + 8192 + q * 2048 + w * 512), 16, 0, 0);
        }
    };
    const int fs = (l15 >> 1) & 3;   // read-side swizzle key
    auto compute = [&](int buf) {
        const unsigned short* as  = SM + buf * 12288;
        const unsigned short* bs0 = as + 4096;
        const unsigned short* bs1 = as + 8192;
        bf16x8 av[4], bv0[4], bv1[4];
#pragma unroll
        for (int i = 0; i < 4; ++i) {
            int ar = (wm * 64 + i * 16 + l15) * 32 + (quad ^ fs) * 8;
            int br = (wn * 64 + i * 16 + l15) * 32 + (quad ^ fs) * 8;
            av[i]  = __builtin_bit_cast(bf16x8, *(const ushort8v*)&as[ar]);
            bv0[i] = __builtin_bit_cast(bf16x8, *(const ushort8v*)&bs0[br]);
            bv1[i] = __builtin_bit_cast(bf16x8, *(const ushort8v*)&bs1[br]);
        }
#pragma unroll
        for (int mi = 0; mi < 4; ++mi)
#pragma unroll
            for (int ni = 0; ni < 4; ++ni) {
                acc0[mi][ni] = __builtin_amdgcn_mfma_f32_16x16x32_bf16(
                    av[mi], bv0[ni], acc0[mi][ni], 0, 0, 0);
                acc1[mi][ni] = __builtin_amdgcn_mfma_f32_16x16x32_bf16(
                    av[mi], bv1[ni], acc1[mi][ni], 0, 0, 0);
            }
    };

    // 3-deep pipeline, counted vmcnt (R5-proven structure; 6 loads/stage).
    // Iter j entry: outstanding = stages {j, j+1} (12 loads). vmcnt(6) -> stage j
    // complete; barrier -> complete across all waves AND all compute(j-1) LDS reads
    // retired -> safe to stage(j+2) into buf (j-1)%3.
    stage(0, 0);
    stage(1, 32);
    for (int j = 0; j < 31; ++j) {
        asm volatile("s_waitcnt vmcnt(6)" ::: "memory");
        __builtin_amdgcn_sched_barrier(0);
        __builtin_amdgcn_s_barrier();
        __builtin_amdgcn_sched_barrier(0);
        int k2 = (j + 2) * 32;
        if (k2 < 1024) stage((j + 2) % 3, k2);
        compute(j % 3);
    }
    asm volatile("s_waitcnt vmcnt(0)" ::: "memory");
    __builtin_amdgcn_sched_barrier(0);
    __builtin_amdgcn_s_barrier();
    __builtin_amdgcn_sched_barrier(0);
    compute(31 % 3);   // buf 1

    if constexpr (FINAL) {
        __syncthreads();                     // all frag reads done -> LDS reusable
        float* eps = (float*)SM + (w << 11); // per-wave 8 KB retile (32 rows x 64 cols)
#pragma unroll
        for (int bb = 0; bb < 2; ++bb) {     // static unroll -> acc index compile-time
            const int b = bb ? b1 : b0;
            const float rsv  = rsA[b];
            const float rsmu = rsv * muA[b];
            f32x4 (&ac)[4][4] = bb ? acc1 : acc0;
#pragma unroll
            for (int ch = 0; ch < 2; ++ch) {
#pragma unroll
                for (int m2 = 0; m2 < 2; ++m2) {
                    int mi = ch * 2 + m2;    // row in chunk = m2*16 + quad*4 + r
#pragma unroll
                    for (int ni = 0; ni < 4; ++ni)
#pragma unroll
                        for (int r = 0; r < 4; ++r)
                            eps[(m2 * 16 + quad * 4 + r) * 64 + ni * 16 + l15] = ac[mi][ni][r];
                }
#pragma unroll
                for (int jj = 0; jj < 8; ++jj) {
                    int row = jj * 4 + quad; // 0..31 within chunk
                    int tt = tm * 128 + wm * 64 + ch * 32 + row;
                    int cc = tn * 128 + wn * 64 + l15 * 4;
                    size_t o2 = (size_t)tt * 512 + cc;
                    size_t o  = ((size_t)b * 1024 + tt) * 512 + cc;
                    f32x4 v    = *(f32x4*)&eps[row * 64 + l15 * 4];
                    ushort4 wv4 = *(const ushort4*)&wlb[o2];
                    ushort4 bv4 = *(const ushort4*)&blb[o2];
                    f32x4 xv   = *(const f32x4*)&x[o];
                    float we[4] = {bf2f(wv4.x), bf2f(wv4.y), bf2f(wv4.z), bf2f(wv4.w)};
                    float be[4] = {bf2f(bv4.x), bf2f(bv4.y), bf2f(bv4.z), bf2f(bv4.w)};
                    f32x4 ov;
#pragma unroll
                    for (int e = 0; e < 4; ++e) {
                        float vv = rsv * v[e] - rsmu * we[e] + be[e];
                        vv = vv > 0.f ? vv : 0.f;
                        ov[e] = xv[e] + vv;
                    }
                    *(f32x4*)&out[o] = ov;
                }
                // eps reuse across ch/bb: same-wave DS ordering + compiler lgkm waits
            }
        }
    } else {
        unsigned short* o16 = (unsigned short*)out;
#pragma unroll
        for (int bb = 0; bb < 2; ++bb) {     // bb==z: 0 -> Wl (no bias), 1 -> Blp (+linb)
            f32x4 (&ac)[4][4] = bb ? acc1 : acc0;
#pragma unroll
            for (int mi = 0; mi < 4; ++mi) {
#pragma unroll
                for (int r = 0; r < 4; ++r) {
                    int tt = tm * 128 + wm * 64 + mi * 16 + quad * 4 + r;
                    float add = bb ? linb[tt] : 0.f;
#pragma unroll
                    for (int ni = 0; ni < 4; ++ni) {
                        int cc = tn * 128 + wn * 64 + ni * 16 + l15;
                        o16[((size_t)bb * 1024 + tt) * 512 + cc] = f2bf(ac[mi][ni][r] + add);
                    }
                }
            }
        }
    }
}

extern "C" void kernel_launch(void* const* d_in, const int* in_sizes, int n_in,
                              void* d_out, int out_size, void* d_ws, size_t ws_size,
                              hipStream_t stream) {
    (void)in_sizes; (void)n_in; (void)out_size; (void)ws_size;
    const float* x    = (const float*)d_in[0];
    const float* lnw  = (const float*)d_in[1];
    const float* lnb  = (const float*)d_in[2];
    const float* linw = (const float*)d_in[3];
    const float* linb = (const float*)d_in[4];
    float* out = (float*)d_out;

    char* ws = (char*)d_ws;
    unsigned short* Wb  = (unsigned short*)ws;                 // 2 MB
    unsigned short* Ht  = (unsigned short*)(ws + (2u << 20));  // 66 MB (66 batches)
    unsigned short* wlb = (unsigned short*)(ws + (68u << 20)); // 1 MB  Wl bf16 [1024][512]
    unsigned short* blb = wlb + 512 * 1024;                    // 1 MB  Blp bf16
    float* psum = (float*)(ws + (72u << 20));                  // 32 KB
    float* psq  = psum + 8192;                                 // 32 KB
    float* mu   = psq + 8192;
    float* rsg  = mu + 64;

    k_prep<<<9472, 256, 0, stream>>>(x, lnw, lnb, linw, Wb, Ht, psum, psq);
    k_stats2<<<64, 128, 0, stream>>>(psum, psq, mu, rsg);
    k_gemm<false><<<dim3(4, 8), 256, 0, stream>>>(Wb, Ht, nullptr, linb,
                                                  nullptr, nullptr, nullptr, nullptr,
                                                  (float*)wlb);
    k_gemm<true><<<1024, 256, 0, stream>>>(Wb, Ht, x, nullptr,
                                           wlb, blb, mu, rsg, out);
}